// Round 10
// baseline (397.922 us; speedup 1.0000x reference)
//
#include <hip/hip_runtime.h>
#include <stdint.h>

#define HW 262144              // 512*512
#define NB 32                  // batch
#define TOPK 4096
#define NTOTAL (NB * HW)       // 8388608
#define GBLK 4096              // elements per block for gather
#define CBLK 16384             // R10: 512 blocks -> 2 blocks/CU (was 1, latency-starved)
#define CBPB 16                // compute blocks per batch (HW/CBLK)

// output zero region: (NB*3*HW + NB*TOPK + NB*HW) floats = 33,685,504
// = 8,421,376 float4s = 134,742,016 bytes (R2/R3 proved this region suffices)
#define OUT_F4 8421376u
#define GTHREADS 524288u       // 2048 blocks * 256 threads in k_gather

typedef float f32x4 __attribute__((ext_vector_type(4)));

// ---------------- ws layout (bytes) ----------------
// d:       uint32[NTOTAL]             @ 0          (33,554,432)
// winners: uint64[NB][8192]           @ 33554432   ( 2,097,152)
// histA:   uint32[NB][16384]          @ 35651584   ( 2,097,152)
// histB:   uint32[NB][16384]          @ 37748736   ( 2,097,152)
// stateA:  uint32[NB][2] (B, rem)     @ 39845888   (       256)
// stateT:  uint32[NB]   (T)           @ 39846144   (       128)
// flag:    uint32[NB]                 @ 39846272   (       128)
// cnt:     uint32[NB]                 @ 39846400   (       128)
// done:    uint32[NB]                 @ 39846528   (       128)
// histA..done contiguous; memset of 4194304+1024 bytes covers all.
#define OFF_WIN 33554432
#define OFF_HA  35651584
#define OFF_HB  37748736
#define OFF_STA 39845888
#define OFF_STT 39846144
#define OFF_FLG 39846272
#define OFF_CNT 39846400
#define OFF_DONE 39846528

__device__ __forceinline__ uint32_t rotl32(uint32_t x, int d) {
  return (x << d) | (x >> (32 - d));
}

// JAX threefry2x32, key = (0, 42). Verified bit-exact R6. DO NOT TOUCH.
__device__ __forceinline__ void threefry2x32_k42(uint32_t x0, uint32_t x1,
                                                 uint32_t& o0, uint32_t& o1) {
  const uint32_t ks0 = 0u;
  const uint32_t ks1 = 42u;
  const uint32_t ks2 = 0x1BD11BDAu ^ 0u ^ 42u;
  x0 += ks0;
  x1 += ks1;
#define TF_ROUND(r) { x0 += x1; x1 = rotl32(x1, (r)); x1 ^= x0; }
  TF_ROUND(13) TF_ROUND(15) TF_ROUND(26) TF_ROUND(6)
  x0 += ks1; x1 += ks2 + 1u;
  TF_ROUND(17) TF_ROUND(29) TF_ROUND(16) TF_ROUND(24)
  x0 += ks2; x1 += ks0 + 2u;
  TF_ROUND(13) TF_ROUND(15) TF_ROUND(26) TF_ROUND(6)
  x0 += ks0; x1 += ks1 + 3u;
  TF_ROUND(17) TF_ROUND(29) TF_ROUND(16) TF_ROUND(24)
  x0 += ks1; x1 += ks2 + 4u;
  TF_ROUND(13) TF_ROUND(15) TF_ROUND(26) TF_ROUND(6)
  x0 += ks2; x1 += ks0 + 5u;
#undef TF_ROUND
  o0 = x0;
  o1 = x1;
}

// Bit-exact Eigen plog_float. Verified absmax=0 in R6. DO NOT TOUCH.
__device__ __forceinline__ float eigen_plogf(float xin) {
#pragma clang fp contract(off)
  uint32_t ux = __float_as_uint(xin);
  int e_int = (int)(ux >> 23) - 126;
  float x = __uint_as_float((ux & 0x007fffffu) | 0x3f000000u);
  float e = (float)e_int;
  const float SQRTHF = 0.707106781186547524f;
  bool m = (x < SQRTHF);
  float tmp = m ? x : 0.0f;
  x = x - 1.0f;
  e = e - (m ? 1.0f : 0.0f);
  x = x + tmp;
  float x2 = x * x;
  float x3 = x2 * x;
  float y  = fmaf(7.0376836292e-2f,  x, -1.1514610310e-1f);
  float y1 = fmaf(-1.2420140846e-1f, x,  1.4249322787e-1f);
  float y2 = fmaf(2.0000714765e-1f,  x, -2.4999993993e-1f);
  y  = fmaf(y,  x,  1.1676998740e-1f);
  y1 = fmaf(y1, x, -1.6668057665e-1f);
  y2 = fmaf(y2, x,  3.3333331174e-1f);
  y  = fmaf(y,  x3, y1);
  y  = fmaf(y,  x3, y2);
  y  = y * x3;
  float ey1 = e * -2.12194440e-4f;
  float t2  = x2 * 0.5f;
  y = y + ey1;
  x = x - t2;
  float ey2 = e * 0.693359375f;
  x = x + y;
  x = x + ey2;
  return x;
}

// Bit-exact numpy SIMD f32 np.log (rational). Verified R6. DO NOT TOUCH.
__device__ __forceinline__ float np_logf(float xin) {
#pragma clang fp contract(off)
  uint32_t ux = __float_as_uint(xin);
  int e2 = (int)(ux >> 23) - 127;
  float mant = __uint_as_float((ux & 0x007fffffu) | 0x3f800000u);
  if (mant >= 1.5f) { mant = mant * 0.5f; e2 += 1; }
  float e = (float)e2;
  float t = mant - 1.0f;
  float num = fmaf(2.589979117907922693523e-02f, t, 3.808837741388407920751e-01f);
  num = fmaf(num, t, 1.480000633400055983228e+00f);
  num = fmaf(num, t, 2.112677543073053063722e+00f);
  num = fmaf(num, t, 9.999999999999998702752e-01f);
  num = num * t;
  float den = fmaf(5.875095403124574342950e-03f, t, 1.546476374983906719538e-01f);
  den = fmaf(den, t, 9.864942958519418960339e-01f);
  den = fmaf(den, t, 2.453006071784736363091e+00f);
  den = fmaf(den, t, 2.612677543073109236779e+00f);
  den = fmaf(den, t, 1.0f);
  float r = num / den;
  return fmaf(e, 0.693147182464599609375f, r);
}

// score -> descending-order uint32 key. Verified R6. DO NOT TOUCH.
__device__ __forceinline__ uint32_t order_key(const float* __restrict__ flows,
                                              int p, uint32_t bits) {
#pragma clang fp contract(off)
  int b = p >> 18;
  int j = p & (HW - 1);
  const float* fb = flows + ((size_t)b << 19);
  float x = fb[j];
  float y = fb[j + HW];
  float xx = x * x;
  float yy = y * y;
  float ss = xx + yy;
  float sq = (float)sqrt((double)ss);
  float dist = (float)((double)sq / (double)0.07f);
  float logits = np_logf(dist + 1e-20f);
  float f = __uint_as_float((bits >> 9) | 0x3f800000u) - 1.0f;
  float u = fmaxf(f, 1.17549435e-38f);
  float g = -eigen_plogf(-eigen_plogf(u));
  float s = logits + g;
  uint32_t mm = __float_as_uint(s);
  mm = (mm & 0x80000000u) ? ~mm : (mm | 0x80000000u);
  return ~mm;
}

// keys + LDS hist + inline per-batch scan (last-of-16-blocks).
// R10: CBLK=16384 -> 512 blocks -> 2 blocks/CU (R9 profile: 1 block/CU gave
// 28% occupancy, 40% VALUBusy, latency-bound). No zero stores here (R9
// showed they do NOT hide in this latency-bound kernel; R8 proved they ride
// fine in gather).
__global__ __launch_bounds__(1024) void k_compute(const float* __restrict__ flows,
                                                  uint32_t* __restrict__ d,
                                                  uint32_t* __restrict__ histA,
                                                  uint32_t* __restrict__ histB,
                                                  uint32_t* __restrict__ stateA,
                                                  uint32_t* __restrict__ stateT,
                                                  uint32_t* __restrict__ flag,
                                                  uint32_t* __restrict__ done) {
  __shared__ uint32_t lh[16384];   // 64 KB; reused as scan scratch afterwards
  __shared__ uint32_t bc[3];       // B, rem, overflow (scan phase)
  __shared__ uint32_t lastflag;
  for (int i = threadIdx.x; i < 16384; i += 1024) lh[i] = 0u;
  __syncthreads();
  int base = blockIdx.x * CBLK;
  int b = base >> 18;
  for (int it = 0; it < CBLK / 1024; ++it) {       // 16 iterations
    int p = base + it * 1024 + threadIdx.x;
    uint32_t o0, o1;
    threefry2x32_k42(0u, (uint32_t)p, o0, o1);
    uint32_t dv = order_key(flows, p, o0 ^ o1);
    d[p] = dv;
    atomicAdd(&lh[dv >> 18], 1u);
  }
  __syncthreads();
  uint32_t* hb = histA + ((uint32_t)b << 14);
  for (int i = threadIdx.x; i < 16384; i += 1024) {
    uint32_t c = lh[i];
    if (c) atomicAdd(&hb[i], c);   // coalesced, 16 blocks/batch contending
  }
  // ---- last-block-done: the 16th block of this batch runs the scan ----
  __syncthreads();                  // implies full vmcnt drain of our stores
  if (threadIdx.x == 0) {
    __threadfence();                // release: d stores + hist atomics visible
    uint32_t prev = atomicAdd(&done[b], 1u);
    lastflag = (prev == CBPB - 1u) ? 1u : 0u;
  }
  __syncthreads();
  if (!lastflag) return;
  __threadfence();                  // acquire: see other blocks' writes
  // ---- scanA (identical arithmetic to R8's k_scanAB) ----
  {
    const uint32_t* h = histA + ((uint32_t)b << 14);
    int sbase = threadIdx.x * 16;
    uint32_t s = 0;
    for (int i = 0; i < 16; ++i) s += h[sbase + i];
    lh[threadIdx.x] = s;
    __syncthreads();
    for (int off = 1; off < 1024; off <<= 1) {
      uint32_t v = (threadIdx.x >= off) ? lh[threadIdx.x - off] : 0u;
      __syncthreads();
      lh[threadIdx.x] += v;
      __syncthreads();
    }
    uint32_t incl = lh[threadIdx.x];
    uint32_t excl = incl - s;
    if (excl < TOPK && TOPK <= incl) {   // exactly one thread per batch
      uint32_t cum = excl;
      for (int i = 0; i < 16; ++i) {
        uint32_t c = h[sbase + i];
        if (cum + c >= TOPK) {
          uint32_t B = (uint32_t)(sbase + i);
          stateA[2 * b] = B;
          stateA[2 * b + 1] = TOPK - cum;          // rank remaining in bin B
          stateT[b] = (B << 18) | 0x3FFFFu;        // end-of-bin threshold
          uint32_t ov = (cum + c > 8192u) ? 1u : 0u;
          flag[b] = ov;                            // winners cap check
          bc[0] = B; bc[1] = TOPK - cum; bc[2] = ov;
          break;
        }
        cum += c;
      }
    }
  }
  __syncthreads();
  if (bc[2] == 0u) return;          // normal case
  // ---- rare fallback: conditioned histogram of bits [4:17] + scanB ----
  uint32_t B = bc[0];
  uint32_t target = bc[1];
  uint32_t* h2 = histB + ((uint32_t)b << 14);
  const uint32_t* db = d + ((size_t)b << 18);
  for (int it = 0; it < HW / 1024; ++it) {
    uint32_t dv = db[it * 1024 + threadIdx.x];
    if ((dv >> 18) == B)
      atomicAdd(&h2[(dv >> 4) & 0x3FFFu], 1u);
  }
  __threadfence();                  // make atomics visible to our own loads
  __syncthreads();
  {
    int sbase = threadIdx.x * 16;
    uint32_t s = 0;
    for (int i = 0; i < 16; ++i) s += h2[sbase + i];
    lh[threadIdx.x] = s;
    __syncthreads();
    for (int off = 1; off < 1024; off <<= 1) {
      uint32_t v = (threadIdx.x >= off) ? lh[threadIdx.x - off] : 0u;
      __syncthreads();
      lh[threadIdx.x] += v;
      __syncthreads();
    }
    uint32_t incl = lh[threadIdx.x];
    uint32_t excl = incl - s;
    if (excl < target && target <= incl) {
      uint32_t cum = excl;
      for (int i = 0; i < 16; ++i) {
        uint32_t c = h2[sbase + i];
        if (cum + c >= target) {
          stateT[b] = (B << 18) | ((uint32_t)(sbase + i) << 4) | 0xFu;
          break;
        }
        cum += c;
      }
    }
  }
}

// LDS-staged winner gather + interleaved output zeroing (R8-proven placement:
// 2048 blocks = full-chip store BW, no barrier coupling with the reads).
__global__ __launch_bounds__(256) void k_gather(const uint32_t* __restrict__ d,
                                                const uint32_t* __restrict__ stateT,
                                                uint32_t* __restrict__ cnt,
                                                unsigned long long* __restrict__ winners,
                                                f32x4* __restrict__ outz) {
  __shared__ unsigned long long buf[GBLK];
  __shared__ uint32_t lcnt;
  __shared__ uint32_t gbase;
  int base = blockIdx.x * GBLK;
  int b = base >> 18;
  uint32_t T = stateT[b];
  uint32_t gt = (uint32_t)blockIdx.x * 256u + threadIdx.x;
  const f32x4 z4 = {0.f, 0.f, 0.f, 0.f};
  if (threadIdx.x == 0) lcnt = 0u;
  __syncthreads();
  for (int it = 0; it < GBLK / 256; ++it) {       // 16 iterations
    int p = base + it * 256 + threadIdx.x;
    uint32_t dv = d[p];
    outz[(uint32_t)it * GTHREADS + gt] = z4;      // zero-fill ride-along
    if (dv <= T) {
      uint32_t pos = atomicAdd(&lcnt, 1u);
      buf[pos] = ((unsigned long long)dv << 32) |
                 (unsigned long long)(p & (HW - 1));
    }
  }
  { uint32_t z = 16u * GTHREADS + gt;             // tail: 32768 float4s
    if (z < OUT_F4) outz[z] = z4; }
  __syncthreads();
  uint32_t n = lcnt;
  if (threadIdx.x == 0 && n) gbase = atomicAdd(&cnt[b], n);
  __syncthreads();
  for (uint32_t i = threadIdx.x; i < n; i += 256) {
    uint32_t pos = gbase + i;
    if (pos < 8192u) winners[(size_t)b * 8192 + pos] = buf[i];
  }
}

// sort each 1024-chunk ascending; 1024 threads = one compare-exchange per
// thread per pass (R8-verified).
__global__ __launch_bounds__(1024) void k_sort1(const uint32_t* __restrict__ cnt,
                                                unsigned long long* __restrict__ winners) {
  __shared__ unsigned long long s[1024];
  int blk = blockIdx.x;
  int b = blk >> 3;
  int c = blk & 7;
  uint32_t n = cnt[b];
  if (n > 8192u) n = 8192u;
  int goff = b * 8192 + c * 1024;
  int t = threadIdx.x;
  s[t] = ((uint32_t)(c * 1024 + t) < n) ? winners[goff + t]
                                        : 0xFFFFFFFFFFFFFFFFull;
  __syncthreads();
  for (int k = 2; k <= 1024; k <<= 1) {
    for (int j = k >> 1; j > 0; j >>= 1) {
      int ixj = t ^ j;
      if (ixj > t) {
        bool up = ((t & k) == 0);
        unsigned long long a = s[t];
        unsigned long long cc = s[ixj];
        if ((a > cc) == up) { s[t] = cc; s[ixj] = a; }
      }
      __syncthreads();
    }
  }
  winners[goff + t] = s[t];
}

// exact rank via 7 binary searches/winner + scatter; 8 blocks per batch
// (R8-verified).
__global__ __launch_bounds__(1024) void k_rank(const unsigned long long* __restrict__ winners,
                                               const float* __restrict__ flows,
                                               float* __restrict__ out0,
                                               float* __restrict__ out_idx,
                                               float* __restrict__ out_masks) {
  __shared__ unsigned long long s[8192];
  int b = blockIdx.x >> 3;
  int part = blockIdx.x & 7;
  for (int i = threadIdx.x; i < 8192; i += 1024)
    s[i] = winners[(size_t)b * 8192 + i];
  __syncthreads();
  const float* fb = flows + ((size_t)b << 19);
  int i = (part << 10) + threadIdx.x;              // this block's winner
  unsigned long long w = s[i];
  if (w != 0xFFFFFFFFFFFFFFFFull) {
    int rank = threadIdx.x;                        // position in own chunk
    for (int c = 0; c < 8; ++c) {
      if (c == part) continue;
      int lo = 0, hi = 1024;
      while (lo < hi) {
        int mid = (lo + hi) >> 1;
        if (s[(c << 10) + mid] < w) lo = mid + 1; else hi = mid;
      }
      rank += lo;
    }
    if (rank < TOPK) {
      uint32_t idx = (uint32_t)(w & 0xFFFFFFFFull);
      out_idx[(size_t)b * TOPK + rank] = (float)idx;
      float x = fb[idx];
      float y = fb[idx + HW];
      size_t o = ((size_t)b * 3) * HW + idx;
      out0[o] = x;
      out0[o + HW] = y;
      out0[o + 2 * HW] = 1.0f;
      out_masks[(size_t)b * HW + idx] = 1.0f;
    }
  }
}

extern "C" void kernel_launch(void* const* d_in, const int* in_sizes, int n_in,
                              void* d_out, int out_size, void* d_ws, size_t ws_size,
                              hipStream_t stream) {
  const float* flows = (const float*)d_in[0];
  float* out = (float*)d_out;
  char* ws = (char*)d_ws;

  uint32_t* d = (uint32_t*)ws;
  unsigned long long* winners = (unsigned long long*)(ws + OFF_WIN);
  uint32_t* histA = (uint32_t*)(ws + OFF_HA);
  uint32_t* histB = (uint32_t*)(ws + OFF_HB);
  uint32_t* stateA = (uint32_t*)(ws + OFF_STA);
  uint32_t* stateT = (uint32_t*)(ws + OFF_STT);
  uint32_t* flag = (uint32_t*)(ws + OFF_FLG);
  uint32_t* cnt = (uint32_t*)(ws + OFF_CNT);
  uint32_t* done = (uint32_t*)(ws + OFF_DONE);

  float* out_idx = out + (size_t)NB * 3 * HW;        // 25,165,824
  float* out_masks = out_idx + (size_t)NB * TOPK;    // 25,296,896

  // hist/state/done workspace memset.
  (void)hipMemsetAsync(ws + OFF_HA, 0, 4194304 + 1024, stream);

  k_compute<<<NTOTAL / CBLK, 1024, 0, stream>>>(flows, d, histA, histB,
                                                stateA, stateT, flag, done);
  k_gather<<<NTOTAL / GBLK, 256, 0, stream>>>(d, stateT, cnt, winners,
                                              (f32x4*)out);
  k_sort1<<<NB * 8, 1024, 0, stream>>>(cnt, winners);
  k_rank<<<NB * 8, 1024, 0, stream>>>(winners, flows, out, out_idx, out_masks);
}

// Round 11
// 295.913 us; speedup vs baseline: 1.3447x; 1.3447x over previous
//
#include <hip/hip_runtime.h>
#include <stdint.h>

#define HW 262144              // 512*512
#define NB 32                  // batch
#define TOPK 4096
#define NTOTAL (NB * HW)       // 8388608
#define GBLK 4096              // elements per block for gather
#define CBLK 32768             // elements per block for k_compute (256 blocks)

// output zero region: (NB*3*HW + NB*TOPK + NB*HW) floats = 33,685,504
// = 8,421,376 float4s = 134,742,016 bytes (R2/R3 proved this region suffices)
#define OUT_F4 8421376u
#define GTHREADS 524288u       // 2048 blocks * 256 threads in k_gather

typedef float f32x4 __attribute__((ext_vector_type(4)));

// ---------------- ws layout (bytes) ----------------
// d:       uint32[NTOTAL]             @ 0          (33,554,432)
// winners: uint64[NB][8192]           @ 33554432   ( 2,097,152)
// histA:   uint32[NB][8192]           @ 35651584   ( 1,048,576 used of 2MB slot)
// histB:   uint32[NB][16384]          @ 37748736   ( 2,097,152)
// stateA:  uint32[NB][2] (B, rem)     @ 39845888   (       256)
// stateT:  uint32[NB]   (T)           @ 39846144   (       128)
// flag:    uint32[NB]                 @ 39846272   (       128)
// cnt:     uint32[NB]                 @ 39846400   (       128)
#define OFF_WIN 33554432
#define OFF_HA  35651584
#define OFF_HB  37748736
#define OFF_STA 39845888
#define OFF_STT 39846144
#define OFF_FLG 39846272
#define OFF_CNT 39846400

__device__ __forceinline__ uint32_t rotl32(uint32_t x, int d) {
  return (x << d) | (x >> (32 - d));
}

// JAX threefry2x32, key = (0, 42). Verified bit-exact R6. DO NOT TOUCH.
__device__ __forceinline__ void threefry2x32_k42(uint32_t x0, uint32_t x1,
                                                 uint32_t& o0, uint32_t& o1) {
  const uint32_t ks0 = 0u;
  const uint32_t ks1 = 42u;
  const uint32_t ks2 = 0x1BD11BDAu ^ 0u ^ 42u;
  x0 += ks0;
  x1 += ks1;
#define TF_ROUND(r) { x0 += x1; x1 = rotl32(x1, (r)); x1 ^= x0; }
  TF_ROUND(13) TF_ROUND(15) TF_ROUND(26) TF_ROUND(6)
  x0 += ks1; x1 += ks2 + 1u;
  TF_ROUND(17) TF_ROUND(29) TF_ROUND(16) TF_ROUND(24)
  x0 += ks2; x1 += ks0 + 2u;
  TF_ROUND(13) TF_ROUND(15) TF_ROUND(26) TF_ROUND(6)
  x0 += ks0; x1 += ks1 + 3u;
  TF_ROUND(17) TF_ROUND(29) TF_ROUND(16) TF_ROUND(24)
  x0 += ks1; x1 += ks2 + 4u;
  TF_ROUND(13) TF_ROUND(15) TF_ROUND(26) TF_ROUND(6)
  x0 += ks2; x1 += ks0 + 5u;
#undef TF_ROUND
  o0 = x0;
  o1 = x1;
}

// Bit-exact Eigen plog_float. Verified absmax=0 in R6. DO NOT TOUCH.
__device__ __forceinline__ float eigen_plogf(float xin) {
#pragma clang fp contract(off)
  uint32_t ux = __float_as_uint(xin);
  int e_int = (int)(ux >> 23) - 126;
  float x = __uint_as_float((ux & 0x007fffffu) | 0x3f000000u);
  float e = (float)e_int;
  const float SQRTHF = 0.707106781186547524f;
  bool m = (x < SQRTHF);
  float tmp = m ? x : 0.0f;
  x = x - 1.0f;
  e = e - (m ? 1.0f : 0.0f);
  x = x + tmp;
  float x2 = x * x;
  float x3 = x2 * x;
  float y  = fmaf(7.0376836292e-2f,  x, -1.1514610310e-1f);
  float y1 = fmaf(-1.2420140846e-1f, x,  1.4249322787e-1f);
  float y2 = fmaf(2.0000714765e-1f,  x, -2.4999993993e-1f);
  y  = fmaf(y,  x,  1.1676998740e-1f);
  y1 = fmaf(y1, x, -1.6668057665e-1f);
  y2 = fmaf(y2, x,  3.3333331174e-1f);
  y  = fmaf(y,  x3, y1);
  y  = fmaf(y,  x3, y2);
  y  = y * x3;
  float ey1 = e * -2.12194440e-4f;
  float t2  = x2 * 0.5f;
  y = y + ey1;
  x = x - t2;
  float ey2 = e * 0.693359375f;
  x = x + y;
  x = x + ey2;
  return x;
}

// Bit-exact numpy SIMD f32 np.log (rational). Verified R6. DO NOT TOUCH.
__device__ __forceinline__ float np_logf(float xin) {
#pragma clang fp contract(off)
  uint32_t ux = __float_as_uint(xin);
  int e2 = (int)(ux >> 23) - 127;
  float mant = __uint_as_float((ux & 0x007fffffu) | 0x3f800000u);
  if (mant >= 1.5f) { mant = mant * 0.5f; e2 += 1; }
  float e = (float)e2;
  float t = mant - 1.0f;
  float num = fmaf(2.589979117907922693523e-02f, t, 3.808837741388407920751e-01f);
  num = fmaf(num, t, 1.480000633400055983228e+00f);
  num = fmaf(num, t, 2.112677543073053063722e+00f);
  num = fmaf(num, t, 9.999999999999998702752e-01f);
  num = num * t;
  float den = fmaf(5.875095403124574342950e-03f, t, 1.546476374983906719538e-01f);
  den = fmaf(den, t, 9.864942958519418960339e-01f);
  den = fmaf(den, t, 2.453006071784736363091e+00f);
  den = fmaf(den, t, 2.612677543073109236779e+00f);
  den = fmaf(den, t, 1.0f);
  float r = num / den;
  return fmaf(e, 0.693147182464599609375f, r);
}

// score -> descending-order uint32 key. Verified R6. DO NOT TOUCH.
__device__ __forceinline__ uint32_t order_key(const float* __restrict__ flows,
                                              int p, uint32_t bits) {
#pragma clang fp contract(off)
  int b = p >> 18;
  int j = p & (HW - 1);
  const float* fb = flows + ((size_t)b << 19);
  float x = fb[j];
  float y = fb[j + HW];
  float xx = x * x;
  float yy = y * y;
  float ss = xx + yy;
  float sq = (float)sqrt((double)ss);
  float dist = (float)((double)sq / (double)0.07f);
  float logits = np_logf(dist + 1e-20f);
  float f = __uint_as_float((bits >> 9) | 0x3f800000u) - 1.0f;
  float u = fmaxf(f, 1.17549435e-38f);
  float g = -eigen_plogf(-eigen_plogf(u));
  float s = logits + g;
  uint32_t mm = __float_as_uint(s);
  mm = (mm & 0x80000000u) ? ~mm : (mm | 0x80000000u);
  return ~mm;
}

// keys + fused TOP-13-BIT histogram in LDS. R11: 8192 bins = 32 KB LDS ->
// two 1024-thread blocks co-resident per CU (66 KB total, was 1 block at
// 64 KB; R9/R10 profiles showed 1 block/CU = latency-starved at 28% occ).
// Same 256-block grid (per-block overheads unchanged), halved hist traffic.
__global__ __launch_bounds__(1024) void k_compute(const float* __restrict__ flows,
                                                  uint32_t* __restrict__ d,
                                                  uint32_t* __restrict__ histA) {
  __shared__ uint32_t lh[8192];    // 32 KB
  for (int i = threadIdx.x; i < 8192; i += 1024) lh[i] = 0u;
  __syncthreads();
  int base = blockIdx.x * CBLK;
  int b = base >> 18;
  for (int it = 0; it < CBLK / 1024; ++it) {
    int p = base + it * 1024 + threadIdx.x;
    uint32_t o0, o1;
    threefry2x32_k42(0u, (uint32_t)p, o0, o1);
    uint32_t dv = order_key(flows, p, o0 ^ o1);
    d[p] = dv;
    atomicAdd(&lh[dv >> 19], 1u);
  }
  __syncthreads();
  uint32_t* hb = histA + ((uint32_t)b << 13);
  for (int i = threadIdx.x; i < 8192; i += 1024) {
    uint32_t c = lh[i];
    if (c) atomicAdd(&hb[i], c);   // coalesced, 8 blocks/batch contending
  }
}

// merged scanA + (rare) histB + scanB: one block per batch. R11: scanA over
// 8192 top-13 bins (8 bins/thread); fallback histograms bits [18:5].
__global__ __launch_bounds__(1024) void k_scanAB(const uint32_t* __restrict__ histA,
                                                 const uint32_t* __restrict__ d,
                                                 uint32_t* __restrict__ histB,
                                                 uint32_t* __restrict__ stateA,
                                                 uint32_t* __restrict__ stateT,
                                                 uint32_t* __restrict__ flag) {
  __shared__ uint32_t ls[1024];
  __shared__ uint32_t bc[3];       // B, rem, overflow
  int b = blockIdx.x;
  // ---- scanA: 8192 bins, 8 per thread ----
  {
    const uint32_t* h = histA + ((uint32_t)b << 13);
    int base = threadIdx.x * 8;
    uint32_t s = 0;
    for (int i = 0; i < 8; ++i) s += h[base + i];
    ls[threadIdx.x] = s;
    __syncthreads();
    for (int off = 1; off < 1024; off <<= 1) {
      uint32_t v = (threadIdx.x >= off) ? ls[threadIdx.x - off] : 0u;
      __syncthreads();
      ls[threadIdx.x] += v;
      __syncthreads();
    }
    uint32_t incl = ls[threadIdx.x];
    uint32_t excl = incl - s;
    if (excl < TOPK && TOPK <= incl) {   // exactly one thread per batch
      uint32_t cum = excl;
      for (int i = 0; i < 8; ++i) {
        uint32_t c = h[base + i];
        if (cum + c >= TOPK) {
          uint32_t B = (uint32_t)(base + i);
          stateA[2 * b] = B;
          stateA[2 * b + 1] = TOPK - cum;          // rank remaining in bin B
          stateT[b] = (B << 19) | 0x7FFFFu;        // end-of-bin threshold
          uint32_t ov = (cum + c > 8192u) ? 1u : 0u;
          flag[b] = ov;                            // winners cap check
          bc[0] = B; bc[1] = TOPK - cum; bc[2] = ov;
          break;
        }
        cum += c;
      }
    }
  }
  __syncthreads();
  if (bc[2] == 0u) return;          // normal case
  // ---- rare fallback: conditioned histogram of bits [18:5], then scanB ----
  uint32_t B = bc[0];
  uint32_t target = bc[1];
  uint32_t* h2 = histB + ((uint32_t)b << 14);
  const uint32_t* db = d + ((size_t)b << 18);
  for (int it = 0; it < HW / 1024; ++it) {
    uint32_t dv = db[it * 1024 + threadIdx.x];
    if ((dv >> 19) == B)
      atomicAdd(&h2[(dv >> 5) & 0x3FFFu], 1u);
  }
  __threadfence();                  // make atomics visible to our own loads
  __syncthreads();
  {
    int base = threadIdx.x * 16;
    uint32_t s = 0;
    for (int i = 0; i < 16; ++i) s += h2[base + i];
    ls[threadIdx.x] = s;
    __syncthreads();
    for (int off = 1; off < 1024; off <<= 1) {
      uint32_t v = (threadIdx.x >= off) ? ls[threadIdx.x - off] : 0u;
      __syncthreads();
      ls[threadIdx.x] += v;
      __syncthreads();
    }
    uint32_t incl = ls[threadIdx.x];
    uint32_t excl = incl - s;
    if (excl < target && target <= incl) {
      uint32_t cum = excl;
      for (int i = 0; i < 16; ++i) {
        uint32_t c = h2[base + i];
        if (cum + c >= target) {
          stateT[b] = (B << 19) | ((uint32_t)(base + i) << 5) | 0x1Fu;
          break;
        }
        cum += c;
      }
    }
  }
}

// LDS-staged winner gather + interleaved output zeroing (R8-proven placement:
// 2048 blocks = full-chip store BW, no barrier coupling with the reads).
__global__ __launch_bounds__(256) void k_gather(const uint32_t* __restrict__ d,
                                                const uint32_t* __restrict__ stateT,
                                                uint32_t* __restrict__ cnt,
                                                unsigned long long* __restrict__ winners,
                                                f32x4* __restrict__ outz) {
  __shared__ unsigned long long buf[GBLK];
  __shared__ uint32_t lcnt;
  __shared__ uint32_t gbase;
  int base = blockIdx.x * GBLK;
  int b = base >> 18;
  uint32_t T = stateT[b];
  uint32_t gt = (uint32_t)blockIdx.x * 256u + threadIdx.x;
  const f32x4 z4 = {0.f, 0.f, 0.f, 0.f};
  if (threadIdx.x == 0) lcnt = 0u;
  __syncthreads();
  for (int it = 0; it < GBLK / 256; ++it) {       // 16 iterations
    int p = base + it * 256 + threadIdx.x;
    uint32_t dv = d[p];
    outz[(uint32_t)it * GTHREADS + gt] = z4;      // zero-fill ride-along
    if (dv <= T) {
      uint32_t pos = atomicAdd(&lcnt, 1u);
      buf[pos] = ((unsigned long long)dv << 32) |
                 (unsigned long long)(p & (HW - 1));
    }
  }
  { uint32_t z = 16u * GTHREADS + gt;             // tail: 32768 float4s
    if (z < OUT_F4) outz[z] = z4; }
  __syncthreads();
  uint32_t n = lcnt;
  if (threadIdx.x == 0 && n) gbase = atomicAdd(&cnt[b], n);
  __syncthreads();
  for (uint32_t i = threadIdx.x; i < n; i += 256) {
    uint32_t pos = gbase + i;
    if (pos < 8192u) winners[(size_t)b * 8192 + pos] = buf[i];
  }
}

// sort each 1024-chunk ascending; 1024 threads = one compare-exchange per
// thread per pass (R8-verified).
__global__ __launch_bounds__(1024) void k_sort1(const uint32_t* __restrict__ cnt,
                                                unsigned long long* __restrict__ winners) {
  __shared__ unsigned long long s[1024];
  int blk = blockIdx.x;
  int b = blk >> 3;
  int c = blk & 7;
  uint32_t n = cnt[b];
  if (n > 8192u) n = 8192u;
  int goff = b * 8192 + c * 1024;
  int t = threadIdx.x;
  s[t] = ((uint32_t)(c * 1024 + t) < n) ? winners[goff + t]
                                        : 0xFFFFFFFFFFFFFFFFull;
  __syncthreads();
  for (int k = 2; k <= 1024; k <<= 1) {
    for (int j = k >> 1; j > 0; j >>= 1) {
      int ixj = t ^ j;
      if (ixj > t) {
        bool up = ((t & k) == 0);
        unsigned long long a = s[t];
        unsigned long long cc = s[ixj];
        if ((a > cc) == up) { s[t] = cc; s[ixj] = a; }
      }
      __syncthreads();
    }
  }
  winners[goff + t] = s[t];
}

// exact rank via 7 binary searches/winner + scatter; 8 blocks per batch
// (R8-verified).
__global__ __launch_bounds__(1024) void k_rank(const unsigned long long* __restrict__ winners,
                                               const float* __restrict__ flows,
                                               float* __restrict__ out0,
                                               float* __restrict__ out_idx,
                                               float* __restrict__ out_masks) {
  __shared__ unsigned long long s[8192];
  int b = blockIdx.x >> 3;
  int part = blockIdx.x & 7;
  for (int i = threadIdx.x; i < 8192; i += 1024)
    s[i] = winners[(size_t)b * 8192 + i];
  __syncthreads();
  const float* fb = flows + ((size_t)b << 19);
  int i = (part << 10) + threadIdx.x;              // this block's winner
  unsigned long long w = s[i];
  if (w != 0xFFFFFFFFFFFFFFFFull) {
    int rank = threadIdx.x;                        // position in own chunk
    for (int c = 0; c < 8; ++c) {
      if (c == part) continue;
      int lo = 0, hi = 1024;
      while (lo < hi) {
        int mid = (lo + hi) >> 1;
        if (s[(c << 10) + mid] < w) lo = mid + 1; else hi = mid;
      }
      rank += lo;
    }
    if (rank < TOPK) {
      uint32_t idx = (uint32_t)(w & 0xFFFFFFFFull);
      out_idx[(size_t)b * TOPK + rank] = (float)idx;
      float x = fb[idx];
      float y = fb[idx + HW];
      size_t o = ((size_t)b * 3) * HW + idx;
      out0[o] = x;
      out0[o + HW] = y;
      out0[o + 2 * HW] = 1.0f;
      out_masks[(size_t)b * HW + idx] = 1.0f;
    }
  }
}

extern "C" void kernel_launch(void* const* d_in, const int* in_sizes, int n_in,
                              void* d_out, int out_size, void* d_ws, size_t ws_size,
                              hipStream_t stream) {
  const float* flows = (const float*)d_in[0];
  float* out = (float*)d_out;
  char* ws = (char*)d_ws;

  uint32_t* d = (uint32_t*)ws;
  unsigned long long* winners = (unsigned long long*)(ws + OFF_WIN);
  uint32_t* histA = (uint32_t*)(ws + OFF_HA);
  uint32_t* histB = (uint32_t*)(ws + OFF_HB);
  uint32_t* stateA = (uint32_t*)(ws + OFF_STA);
  uint32_t* stateT = (uint32_t*)(ws + OFF_STT);
  uint32_t* flag = (uint32_t*)(ws + OFF_FLG);
  uint32_t* cnt = (uint32_t*)(ws + OFF_CNT);

  float* out_idx = out + (size_t)NB * 3 * HW;        // 25,165,824
  float* out_masks = out_idx + (size_t)NB * TOPK;    // 25,296,896

  // Output zeroing rides inside k_gather (R8-proven). hist/state memset stays.
  (void)hipMemsetAsync(ws + OFF_HA, 0, 4194304 + 1024, stream);

  k_compute<<<NTOTAL / CBLK, 1024, 0, stream>>>(flows, d, histA);
  k_scanAB<<<NB, 1024, 0, stream>>>(histA, d, histB, stateA, stateT, flag);
  k_gather<<<NTOTAL / GBLK, 256, 0, stream>>>(d, stateT, cnt, winners,
                                              (f32x4*)out);
  k_sort1<<<NB * 8, 1024, 0, stream>>>(cnt, winners);
  k_rank<<<NB * 8, 1024, 0, stream>>>(winners, flows, out, out_idx, out_masks);
}

// Round 12
// 294.361 us; speedup vs baseline: 1.3518x; 1.0053x over previous
//
#include <hip/hip_runtime.h>
#include <stdint.h>

#define HW 262144              // 512*512
#define NB 32                  // batch
#define TOPK 4096
#define NTOTAL (NB * HW)       // 8388608
#define GBLK 4096              // elements per block for gather
#define CBLK 32768             // elements per block for k_compute (256 blocks)

// output zero region: (NB*3*HW + NB*TOPK + NB*HW) floats = 33,685,504
// = 8,421,376 float4s = 134,742,016 bytes (R2/R3 proved this region suffices)
#define OUT_F4 8421376u
#define GTHREADS 524288u       // 2048 blocks * 256 threads in k_gather

typedef float f32x4 __attribute__((ext_vector_type(4)));

// ---------------- ws layout (bytes) ----------------
// d:       uint32[NTOTAL]             @ 0          (33,554,432)
// winners: uint64[NB][8192]           @ 33554432   ( 2,097,152)
// histP:   uint16[256][8192]          @ 35651584   ( 4,194,304) private hists
//          (no pre-zero needed: every bin stored; u16 safe: count<=CBLK=32768)
// stateA:  uint32[NB][2] (B, rem)     @ 39845888   (       256)
// stateT:  uint32[NB]   (T)           @ 39846144   (       128)
// flag:    uint32[NB]                 @ 39846272   (       128)
// cnt:     uint32[NB]                 @ 39846400   (       128)  zeroed by scanAB
#define OFF_WIN 33554432
#define OFF_HP  35651584
#define OFF_STA 39845888
#define OFF_STT 39846144
#define OFF_FLG 39846272
#define OFF_CNT 39846400

__device__ __forceinline__ uint32_t rotl32(uint32_t x, int d) {
  return (x << d) | (x >> (32 - d));
}

// JAX threefry2x32, key = (0, 42). Verified bit-exact R6. DO NOT TOUCH.
__device__ __forceinline__ void threefry2x32_k42(uint32_t x0, uint32_t x1,
                                                 uint32_t& o0, uint32_t& o1) {
  const uint32_t ks0 = 0u;
  const uint32_t ks1 = 42u;
  const uint32_t ks2 = 0x1BD11BDAu ^ 0u ^ 42u;
  x0 += ks0;
  x1 += ks1;
#define TF_ROUND(r) { x0 += x1; x1 = rotl32(x1, (r)); x1 ^= x0; }
  TF_ROUND(13) TF_ROUND(15) TF_ROUND(26) TF_ROUND(6)
  x0 += ks1; x1 += ks2 + 1u;
  TF_ROUND(17) TF_ROUND(29) TF_ROUND(16) TF_ROUND(24)
  x0 += ks2; x1 += ks0 + 2u;
  TF_ROUND(13) TF_ROUND(15) TF_ROUND(26) TF_ROUND(6)
  x0 += ks0; x1 += ks1 + 3u;
  TF_ROUND(17) TF_ROUND(29) TF_ROUND(16) TF_ROUND(24)
  x0 += ks1; x1 += ks2 + 4u;
  TF_ROUND(13) TF_ROUND(15) TF_ROUND(26) TF_ROUND(6)
  x0 += ks2; x1 += ks0 + 5u;
#undef TF_ROUND
  o0 = x0;
  o1 = x1;
}

// Bit-exact Eigen plog_float. Verified absmax=0 in R6. DO NOT TOUCH.
__device__ __forceinline__ float eigen_plogf(float xin) {
#pragma clang fp contract(off)
  uint32_t ux = __float_as_uint(xin);
  int e_int = (int)(ux >> 23) - 126;
  float x = __uint_as_float((ux & 0x007fffffu) | 0x3f000000u);
  float e = (float)e_int;
  const float SQRTHF = 0.707106781186547524f;
  bool m = (x < SQRTHF);
  float tmp = m ? x : 0.0f;
  x = x - 1.0f;
  e = e - (m ? 1.0f : 0.0f);
  x = x + tmp;
  float x2 = x * x;
  float x3 = x2 * x;
  float y  = fmaf(7.0376836292e-2f,  x, -1.1514610310e-1f);
  float y1 = fmaf(-1.2420140846e-1f, x,  1.4249322787e-1f);
  float y2 = fmaf(2.0000714765e-1f,  x, -2.4999993993e-1f);
  y  = fmaf(y,  x,  1.1676998740e-1f);
  y1 = fmaf(y1, x, -1.6668057665e-1f);
  y2 = fmaf(y2, x,  3.3333331174e-1f);
  y  = fmaf(y,  x3, y1);
  y  = fmaf(y,  x3, y2);
  y  = y * x3;
  float ey1 = e * -2.12194440e-4f;
  float t2  = x2 * 0.5f;
  y = y + ey1;
  x = x - t2;
  float ey2 = e * 0.693359375f;
  x = x + y;
  x = x + ey2;
  return x;
}

// Bit-exact numpy SIMD f32 np.log (rational). Verified R6. DO NOT TOUCH.
__device__ __forceinline__ float np_logf(float xin) {
#pragma clang fp contract(off)
  uint32_t ux = __float_as_uint(xin);
  int e2 = (int)(ux >> 23) - 127;
  float mant = __uint_as_float((ux & 0x007fffffu) | 0x3f800000u);
  if (mant >= 1.5f) { mant = mant * 0.5f; e2 += 1; }
  float e = (float)e2;
  float t = mant - 1.0f;
  float num = fmaf(2.589979117907922693523e-02f, t, 3.808837741388407920751e-01f);
  num = fmaf(num, t, 1.480000633400055983228e+00f);
  num = fmaf(num, t, 2.112677543073053063722e+00f);
  num = fmaf(num, t, 9.999999999999998702752e-01f);
  num = num * t;
  float den = fmaf(5.875095403124574342950e-03f, t, 1.546476374983906719538e-01f);
  den = fmaf(den, t, 9.864942958519418960339e-01f);
  den = fmaf(den, t, 2.453006071784736363091e+00f);
  den = fmaf(den, t, 2.612677543073109236779e+00f);
  den = fmaf(den, t, 1.0f);
  float r = num / den;
  return fmaf(e, 0.693147182464599609375f, r);
}

// score -> descending-order uint32 key. Verified R6. DO NOT TOUCH.
__device__ __forceinline__ uint32_t order_key(const float* __restrict__ flows,
                                              int p, uint32_t bits) {
#pragma clang fp contract(off)
  int b = p >> 18;
  int j = p & (HW - 1);
  const float* fb = flows + ((size_t)b << 19);
  float x = fb[j];
  float y = fb[j + HW];
  float xx = x * x;
  float yy = y * y;
  float ss = xx + yy;
  float sq = (float)sqrt((double)ss);
  float dist = (float)((double)sq / (double)0.07f);
  float logits = np_logf(dist + 1e-20f);
  float f = __uint_as_float((bits >> 9) | 0x3f800000u) - 1.0f;
  float u = fmaxf(f, 1.17549435e-38f);
  float g = -eigen_plogf(-eigen_plogf(u));
  float s = logits + g;
  uint32_t mm = __float_as_uint(s);
  mm = (mm & 0x80000000u) ? ~mm : (mm | 0x80000000u);
  return ~mm;
}

// keys + fused top-13-bit histogram in LDS (32 KB -> 2 blocks/CU, R11).
// R12: flush to a PRIVATE per-block u16 histogram (plain coalesced stores,
// no global atomics, no pre-zeroing -> the ws memset dispatch is eliminated).
// u16 is provably safe: a block's bin count <= CBLK = 32768 < 65536.
__global__ __launch_bounds__(1024) void k_compute(const float* __restrict__ flows,
                                                  uint32_t* __restrict__ d,
                                                  uint16_t* __restrict__ histP) {
  __shared__ uint32_t lh[8192];    // 32 KB
  for (int i = threadIdx.x; i < 8192; i += 1024) lh[i] = 0u;
  __syncthreads();
  int base = blockIdx.x * CBLK;
  for (int it = 0; it < CBLK / 1024; ++it) {
    int p = base + it * 1024 + threadIdx.x;
    uint32_t o0, o1;
    threefry2x32_k42(0u, (uint32_t)p, o0, o1);
    uint32_t dv = order_key(flows, p, o0 ^ o1);
    d[p] = dv;
    atomicAdd(&lh[dv >> 19], 1u);
  }
  __syncthreads();
  uint16_t* hb = histP + ((uint32_t)blockIdx.x << 13);
  for (int i = threadIdx.x; i < 8192; i += 1024)
    hb[i] = (uint16_t)lh[i];       // every bin written -> no pre-zero needed
}

// merged scanA + (rare) LDS-histB + scanB: one block per batch.
// R12: sums the 8 private u16 copies per bin (integer-exact same totals as
// the old atomic flush); zeroes cnt[b] for gather; rare fallback histogram
// lives in LDS (64 KB, zeroed here) -> global histB deleted.
__global__ __launch_bounds__(1024) void k_scanAB(const uint16_t* __restrict__ histP,
                                                 const uint32_t* __restrict__ d,
                                                 uint32_t* __restrict__ stateA,
                                                 uint32_t* __restrict__ stateT,
                                                 uint32_t* __restrict__ flag,
                                                 uint32_t* __restrict__ cnt) {
  __shared__ uint32_t ls[1024];
  __shared__ uint32_t lh2[16384];  // 64 KB, fallback histogram
  __shared__ uint32_t bc[3];       // B, rem, overflow
  int b = blockIdx.x;
  if (threadIdx.x == 0) cnt[b] = 0u;   // replaces ws memset (gather runs later)
  // ---- scanA: 8192 bins, 8 per thread, summed across the 8 private copies ----
  {
    const uint16_t* hp = histP + ((uint32_t)(b * 8) << 13);   // copies 8b..8b+7
    int base = threadIdx.x * 8;
    uint32_t bs[8];
    uint32_t s = 0;
#pragma unroll
    for (int i = 0; i < 8; ++i) {
      uint32_t t = 0;
#pragma unroll
      for (int c = 0; c < 8; ++c) t += hp[(c << 13) + base + i];
      bs[i] = t;
      s += t;
    }
    ls[threadIdx.x] = s;
    __syncthreads();
    for (int off = 1; off < 1024; off <<= 1) {
      uint32_t v = (threadIdx.x >= off) ? ls[threadIdx.x - off] : 0u;
      __syncthreads();
      ls[threadIdx.x] += v;
      __syncthreads();
    }
    uint32_t incl = ls[threadIdx.x];
    uint32_t excl = incl - s;
    if (excl < TOPK && TOPK <= incl) {   // exactly one thread per batch
      uint32_t cum = excl;
#pragma unroll
      for (int i = 0; i < 8; ++i) {
        uint32_t c = bs[i];
        if (cum + c >= TOPK) {
          uint32_t B = (uint32_t)(base + i);
          stateA[2 * b] = B;
          stateA[2 * b + 1] = TOPK - cum;          // rank remaining in bin B
          stateT[b] = (B << 19) | 0x7FFFFu;        // end-of-bin threshold
          uint32_t ov = (cum + c > 8192u) ? 1u : 0u;
          flag[b] = ov;                            // winners cap check
          bc[0] = B; bc[1] = TOPK - cum; bc[2] = ov;
          break;
        }
        cum += c;
      }
    }
  }
  __syncthreads();
  if (bc[2] == 0u) return;          // normal case
  // ---- rare fallback: conditioned LDS histogram of bits [18:5], then scanB ----
  uint32_t B = bc[0];
  uint32_t target = bc[1];
  for (int i = threadIdx.x; i < 16384; i += 1024) lh2[i] = 0u;
  __syncthreads();
  const uint32_t* db = d + ((size_t)b << 18);
  for (int it = 0; it < HW / 1024; ++it) {
    uint32_t dv = db[it * 1024 + threadIdx.x];
    if ((dv >> 19) == B)
      atomicAdd(&lh2[(dv >> 5) & 0x3FFFu], 1u);
  }
  __syncthreads();
  {
    int base = threadIdx.x * 16;
    uint32_t s = 0;
    for (int i = 0; i < 16; ++i) s += lh2[base + i];
    ls[threadIdx.x] = s;
    __syncthreads();
    for (int off = 1; off < 1024; off <<= 1) {
      uint32_t v = (threadIdx.x >= off) ? ls[threadIdx.x - off] : 0u;
      __syncthreads();
      ls[threadIdx.x] += v;
      __syncthreads();
    }
    uint32_t incl = ls[threadIdx.x];
    uint32_t excl = incl - s;
    if (excl < target && target <= incl) {
      uint32_t cum = excl;
      for (int i = 0; i < 16; ++i) {
        uint32_t c = lh2[base + i];
        if (cum + c >= target) {
          stateT[b] = (B << 19) | ((uint32_t)(base + i) << 5) | 0x1Fu;
          break;
        }
        cum += c;
      }
    }
  }
}

// LDS-staged winner gather + interleaved output zeroing (R8-proven placement:
// 2048 blocks = full-chip store BW, no barrier coupling with the reads).
__global__ __launch_bounds__(256) void k_gather(const uint32_t* __restrict__ d,
                                                const uint32_t* __restrict__ stateT,
                                                uint32_t* __restrict__ cnt,
                                                unsigned long long* __restrict__ winners,
                                                f32x4* __restrict__ outz) {
  __shared__ unsigned long long buf[GBLK];
  __shared__ uint32_t lcnt;
  __shared__ uint32_t gbase;
  int base = blockIdx.x * GBLK;
  int b = base >> 18;
  uint32_t T = stateT[b];
  uint32_t gt = (uint32_t)blockIdx.x * 256u + threadIdx.x;
  const f32x4 z4 = {0.f, 0.f, 0.f, 0.f};
  if (threadIdx.x == 0) lcnt = 0u;
  __syncthreads();
  for (int it = 0; it < GBLK / 256; ++it) {       // 16 iterations
    int p = base + it * 256 + threadIdx.x;
    uint32_t dv = d[p];
    outz[(uint32_t)it * GTHREADS + gt] = z4;      // zero-fill ride-along
    if (dv <= T) {
      uint32_t pos = atomicAdd(&lcnt, 1u);
      buf[pos] = ((unsigned long long)dv << 32) |
                 (unsigned long long)(p & (HW - 1));
    }
  }
  { uint32_t z = 16u * GTHREADS + gt;             // tail: 32768 float4s
    if (z < OUT_F4) outz[z] = z4; }
  __syncthreads();
  uint32_t n = lcnt;
  if (threadIdx.x == 0 && n) gbase = atomicAdd(&cnt[b], n);
  __syncthreads();
  for (uint32_t i = threadIdx.x; i < n; i += 256) {
    uint32_t pos = gbase + i;
    if (pos < 8192u) winners[(size_t)b * 8192 + pos] = buf[i];
  }
}

// sort each 1024-chunk ascending; 1024 threads = one compare-exchange per
// thread per pass (R8-verified).
__global__ __launch_bounds__(1024) void k_sort1(const uint32_t* __restrict__ cnt,
                                                unsigned long long* __restrict__ winners) {
  __shared__ unsigned long long s[1024];
  int blk = blockIdx.x;
  int b = blk >> 3;
  int c = blk & 7;
  uint32_t n = cnt[b];
  if (n > 8192u) n = 8192u;
  int goff = b * 8192 + c * 1024;
  int t = threadIdx.x;
  s[t] = ((uint32_t)(c * 1024 + t) < n) ? winners[goff + t]
                                        : 0xFFFFFFFFFFFFFFFFull;
  __syncthreads();
  for (int k = 2; k <= 1024; k <<= 1) {
    for (int j = k >> 1; j > 0; j >>= 1) {
      int ixj = t ^ j;
      if (ixj > t) {
        bool up = ((t & k) == 0);
        unsigned long long a = s[t];
        unsigned long long cc = s[ixj];
        if ((a > cc) == up) { s[t] = cc; s[ixj] = a; }
      }
      __syncthreads();
    }
  }
  winners[goff + t] = s[t];
}

// exact rank via 7 binary searches/winner + scatter; 8 blocks per batch
// (R8-verified).
__global__ __launch_bounds__(1024) void k_rank(const unsigned long long* __restrict__ winners,
                                               const float* __restrict__ flows,
                                               float* __restrict__ out0,
                                               float* __restrict__ out_idx,
                                               float* __restrict__ out_masks) {
  __shared__ unsigned long long s[8192];
  int b = blockIdx.x >> 3;
  int part = blockIdx.x & 7;
  for (int i = threadIdx.x; i < 8192; i += 1024)
    s[i] = winners[(size_t)b * 8192 + i];
  __syncthreads();
  const float* fb = flows + ((size_t)b << 19);
  int i = (part << 10) + threadIdx.x;              // this block's winner
  unsigned long long w = s[i];
  if (w != 0xFFFFFFFFFFFFFFFFull) {
    int rank = threadIdx.x;                        // position in own chunk
    for (int c = 0; c < 8; ++c) {
      if (c == part) continue;
      int lo = 0, hi = 1024;
      while (lo < hi) {
        int mid = (lo + hi) >> 1;
        if (s[(c << 10) + mid] < w) lo = mid + 1; else hi = mid;
      }
      rank += lo;
    }
    if (rank < TOPK) {
      uint32_t idx = (uint32_t)(w & 0xFFFFFFFFull);
      out_idx[(size_t)b * TOPK + rank] = (float)idx;
      float x = fb[idx];
      float y = fb[idx + HW];
      size_t o = ((size_t)b * 3) * HW + idx;
      out0[o] = x;
      out0[o + HW] = y;
      out0[o + 2 * HW] = 1.0f;
      out_masks[(size_t)b * HW + idx] = 1.0f;
    }
  }
}

extern "C" void kernel_launch(void* const* d_in, const int* in_sizes, int n_in,
                              void* d_out, int out_size, void* d_ws, size_t ws_size,
                              hipStream_t stream) {
  const float* flows = (const float*)d_in[0];
  float* out = (float*)d_out;
  char* ws = (char*)d_ws;

  uint32_t* d = (uint32_t*)ws;
  unsigned long long* winners = (unsigned long long*)(ws + OFF_WIN);
  uint16_t* histP = (uint16_t*)(ws + OFF_HP);
  uint32_t* stateA = (uint32_t*)(ws + OFF_STA);
  uint32_t* stateT = (uint32_t*)(ws + OFF_STT);
  uint32_t* flag = (uint32_t*)(ws + OFF_FLG);
  uint32_t* cnt = (uint32_t*)(ws + OFF_CNT);

  float* out_idx = out + (size_t)NB * 3 * HW;        // 25,165,824
  float* out_masks = out_idx + (size_t)NB * TOPK;    // 25,296,896

  // No memsets at all (R12): private hists need no pre-zero (every bin
  // stored), cnt is zeroed by k_scanAB, fallback hist lives in LDS.
  k_compute<<<NTOTAL / CBLK, 1024, 0, stream>>>(flows, d, histP);
  k_scanAB<<<NB, 1024, 0, stream>>>(histP, d, stateA, stateT, flag, cnt);
  k_gather<<<NTOTAL / GBLK, 256, 0, stream>>>(d, stateT, cnt, winners,
                                              (f32x4*)out);
  k_sort1<<<NB * 8, 1024, 0, stream>>>(cnt, winners);
  k_rank<<<NB * 8, 1024, 0, stream>>>(winners, flows, out, out_idx, out_masks);
}

// Round 13
// 291.505 us; speedup vs baseline: 1.3651x; 1.0098x over previous
//
#include <hip/hip_runtime.h>
#include <stdint.h>

#define HW 262144              // 512*512
#define NB 32                  // batch
#define TOPK 4096
#define NTOTAL (NB * HW)       // 8388608
#define GBLK 4096              // elements per block for gather
#define CBLK 32768             // elements per block for k_compute (256 blocks)

// output zero region: (NB*3*HW + NB*TOPK + NB*HW) floats = 33,685,504
// = 8,421,376 float4s = 134,742,016 bytes (R2/R3 proved this region suffices)
#define OUT_F4 8421376u
#define GTHREADS 524288u       // 2048 blocks * 256 threads in k_gather

typedef float f32x4 __attribute__((ext_vector_type(4)));

// ---------------- ws layout (bytes) ----------------
// d:       uint32[NTOTAL]             @ 0          (33,554,432)
// winners: uint64[NB][8192]           @ 33554432   ( 2,097,152)
// histP:   uint16[256][8192]          @ 35651584   ( 4,194,304) private hists
//          (no pre-zero needed: every bin stored; u16 safe: count<=CBLK=32768)
// stateA:  uint32[NB][2] (B, rem)     @ 39845888   (       256)
// stateT:  uint32[NB]   (T)           @ 39846144   (       128)
// flag:    uint32[NB]                 @ 39846272   (       128)
// cnt:     uint32[NB]                 @ 39846400   (       128)  zeroed by scanAB
#define OFF_WIN 33554432
#define OFF_HP  35651584
#define OFF_STA 39845888
#define OFF_STT 39846144
#define OFF_FLG 39846272
#define OFF_CNT 39846400

__device__ __forceinline__ uint32_t rotl32(uint32_t x, int d) {
  return (x << d) | (x >> (32 - d));
}

// JAX threefry2x32, key = (0, 42). Verified bit-exact R6. DO NOT TOUCH.
__device__ __forceinline__ void threefry2x32_k42(uint32_t x0, uint32_t x1,
                                                 uint32_t& o0, uint32_t& o1) {
  const uint32_t ks0 = 0u;
  const uint32_t ks1 = 42u;
  const uint32_t ks2 = 0x1BD11BDAu ^ 0u ^ 42u;
  x0 += ks0;
  x1 += ks1;
#define TF_ROUND(r) { x0 += x1; x1 = rotl32(x1, (r)); x1 ^= x0; }
  TF_ROUND(13) TF_ROUND(15) TF_ROUND(26) TF_ROUND(6)
  x0 += ks1; x1 += ks2 + 1u;
  TF_ROUND(17) TF_ROUND(29) TF_ROUND(16) TF_ROUND(24)
  x0 += ks2; x1 += ks0 + 2u;
  TF_ROUND(13) TF_ROUND(15) TF_ROUND(26) TF_ROUND(6)
  x0 += ks0; x1 += ks1 + 3u;
  TF_ROUND(17) TF_ROUND(29) TF_ROUND(16) TF_ROUND(24)
  x0 += ks1; x1 += ks2 + 4u;
  TF_ROUND(13) TF_ROUND(15) TF_ROUND(26) TF_ROUND(6)
  x0 += ks2; x1 += ks0 + 5u;
#undef TF_ROUND
  o0 = x0;
  o1 = x1;
}

// Bit-exact Eigen plog_float. Verified absmax=0 in R6. DO NOT TOUCH.
__device__ __forceinline__ float eigen_plogf(float xin) {
#pragma clang fp contract(off)
  uint32_t ux = __float_as_uint(xin);
  int e_int = (int)(ux >> 23) - 126;
  float x = __uint_as_float((ux & 0x007fffffu) | 0x3f000000u);
  float e = (float)e_int;
  const float SQRTHF = 0.707106781186547524f;
  bool m = (x < SQRTHF);
  float tmp = m ? x : 0.0f;
  x = x - 1.0f;
  e = e - (m ? 1.0f : 0.0f);
  x = x + tmp;
  float x2 = x * x;
  float x3 = x2 * x;
  float y  = fmaf(7.0376836292e-2f,  x, -1.1514610310e-1f);
  float y1 = fmaf(-1.2420140846e-1f, x,  1.4249322787e-1f);
  float y2 = fmaf(2.0000714765e-1f,  x, -2.4999993993e-1f);
  y  = fmaf(y,  x,  1.1676998740e-1f);
  y1 = fmaf(y1, x, -1.6668057665e-1f);
  y2 = fmaf(y2, x,  3.3333331174e-1f);
  y  = fmaf(y,  x3, y1);
  y  = fmaf(y,  x3, y2);
  y  = y * x3;
  float ey1 = e * -2.12194440e-4f;
  float t2  = x2 * 0.5f;
  y = y + ey1;
  x = x - t2;
  float ey2 = e * 0.693359375f;
  x = x + y;
  x = x + ey2;
  return x;
}

// Bit-exact numpy SIMD f32 np.log (rational). Verified R6. DO NOT TOUCH.
__device__ __forceinline__ float np_logf(float xin) {
#pragma clang fp contract(off)
  uint32_t ux = __float_as_uint(xin);
  int e2 = (int)(ux >> 23) - 127;
  float mant = __uint_as_float((ux & 0x007fffffu) | 0x3f800000u);
  if (mant >= 1.5f) { mant = mant * 0.5f; e2 += 1; }
  float e = (float)e2;
  float t = mant - 1.0f;
  float num = fmaf(2.589979117907922693523e-02f, t, 3.808837741388407920751e-01f);
  num = fmaf(num, t, 1.480000633400055983228e+00f);
  num = fmaf(num, t, 2.112677543073053063722e+00f);
  num = fmaf(num, t, 9.999999999999998702752e-01f);
  num = num * t;
  float den = fmaf(5.875095403124574342950e-03f, t, 1.546476374983906719538e-01f);
  den = fmaf(den, t, 9.864942958519418960339e-01f);
  den = fmaf(den, t, 2.453006071784736363091e+00f);
  den = fmaf(den, t, 2.612677543073109236779e+00f);
  den = fmaf(den, t, 1.0f);
  float r = num / den;
  return fmaf(e, 0.693147182464599609375f, r);
}

// score -> descending-order uint32 key. Verified R6. DO NOT TOUCH.
__device__ __forceinline__ uint32_t order_key(const float* __restrict__ flows,
                                              int p, uint32_t bits) {
#pragma clang fp contract(off)
  int b = p >> 18;
  int j = p & (HW - 1);
  const float* fb = flows + ((size_t)b << 19);
  float x = fb[j];
  float y = fb[j + HW];
  float xx = x * x;
  float yy = y * y;
  float ss = xx + yy;
  float sq = (float)sqrt((double)ss);
  float dist = (float)((double)sq / (double)0.07f);
  float logits = np_logf(dist + 1e-20f);
  float f = __uint_as_float((bits >> 9) | 0x3f800000u) - 1.0f;
  float u = fmaxf(f, 1.17549435e-38f);
  float g = -eigen_plogf(-eigen_plogf(u));
  float s = logits + g;
  uint32_t mm = __float_as_uint(s);
  mm = (mm & 0x80000000u) ? ~mm : (mm | 0x80000000u);
  return ~mm;
}

// keys + fused top-13-bit histogram in LDS (32 KB -> 2 blocks/CU, R11) +
// private u16 hist flush (R12, no atomics/memset).
// R13: TWO adjacent elements per thread per iteration — two independent
// threefry->log->log dependency chains interleave in the scheduler (the
// kernel is chain-latency-bound: issue floor ~19us vs ~60-70us measured).
// Adjacent d[p],d[p+1] stores merge to 8B. Identical per-element math.
__global__ __launch_bounds__(1024) void k_compute(const float* __restrict__ flows,
                                                  uint32_t* __restrict__ d,
                                                  uint16_t* __restrict__ histP) {
  __shared__ uint32_t lh[8192];    // 32 KB
  for (int i = threadIdx.x; i < 8192; i += 1024) lh[i] = 0u;
  __syncthreads();
  int base = blockIdx.x * CBLK;
  for (int it = 0; it < CBLK / 2048; ++it) {     // 16 iterations, 2 elems each
    int p0 = base + it * 2048 + (threadIdx.x << 1);
    int p1 = p0 + 1;
    uint32_t a0, a1, b0, b1;
    threefry2x32_k42(0u, (uint32_t)p0, a0, a1);
    threefry2x32_k42(0u, (uint32_t)p1, b0, b1);
    uint32_t dv0 = order_key(flows, p0, a0 ^ a1);
    uint32_t dv1 = order_key(flows, p1, b0 ^ b1);
    d[p0] = dv0;
    d[p1] = dv1;
    atomicAdd(&lh[dv0 >> 19], 1u);
    atomicAdd(&lh[dv1 >> 19], 1u);
  }
  __syncthreads();
  uint16_t* hb = histP + ((uint32_t)blockIdx.x << 13);
  for (int i = threadIdx.x; i < 8192; i += 1024)
    hb[i] = (uint16_t)lh[i];       // every bin written -> no pre-zero needed
}

// merged scanA + (rare) LDS-histB + scanB: one block per batch (R12).
__global__ __launch_bounds__(1024) void k_scanAB(const uint16_t* __restrict__ histP,
                                                 const uint32_t* __restrict__ d,
                                                 uint32_t* __restrict__ stateA,
                                                 uint32_t* __restrict__ stateT,
                                                 uint32_t* __restrict__ flag,
                                                 uint32_t* __restrict__ cnt) {
  __shared__ uint32_t ls[1024];
  __shared__ uint32_t lh2[16384];  // 64 KB, fallback histogram
  __shared__ uint32_t bc[3];       // B, rem, overflow
  int b = blockIdx.x;
  if (threadIdx.x == 0) cnt[b] = 0u;   // replaces ws memset (gather runs later)
  // ---- scanA: 8192 bins, 8 per thread, summed across the 8 private copies ----
  {
    const uint16_t* hp = histP + ((uint32_t)(b * 8) << 13);   // copies 8b..8b+7
    int base = threadIdx.x * 8;
    uint32_t bs[8];
    uint32_t s = 0;
#pragma unroll
    for (int i = 0; i < 8; ++i) {
      uint32_t t = 0;
#pragma unroll
      for (int c = 0; c < 8; ++c) t += hp[(c << 13) + base + i];
      bs[i] = t;
      s += t;
    }
    ls[threadIdx.x] = s;
    __syncthreads();
    for (int off = 1; off < 1024; off <<= 1) {
      uint32_t v = (threadIdx.x >= off) ? ls[threadIdx.x - off] : 0u;
      __syncthreads();
      ls[threadIdx.x] += v;
      __syncthreads();
    }
    uint32_t incl = ls[threadIdx.x];
    uint32_t excl = incl - s;
    if (excl < TOPK && TOPK <= incl) {   // exactly one thread per batch
      uint32_t cum = excl;
#pragma unroll
      for (int i = 0; i < 8; ++i) {
        uint32_t c = bs[i];
        if (cum + c >= TOPK) {
          uint32_t B = (uint32_t)(base + i);
          stateA[2 * b] = B;
          stateA[2 * b + 1] = TOPK - cum;          // rank remaining in bin B
          stateT[b] = (B << 19) | 0x7FFFFu;        // end-of-bin threshold
          uint32_t ov = (cum + c > 8192u) ? 1u : 0u;
          flag[b] = ov;                            // winners cap check
          bc[0] = B; bc[1] = TOPK - cum; bc[2] = ov;
          break;
        }
        cum += c;
      }
    }
  }
  __syncthreads();
  if (bc[2] == 0u) return;          // normal case
  // ---- rare fallback: conditioned LDS histogram of bits [18:5], then scanB ----
  uint32_t B = bc[0];
  uint32_t target = bc[1];
  for (int i = threadIdx.x; i < 16384; i += 1024) lh2[i] = 0u;
  __syncthreads();
  const uint32_t* db = d + ((size_t)b << 18);
  for (int it = 0; it < HW / 1024; ++it) {
    uint32_t dv = db[it * 1024 + threadIdx.x];
    if ((dv >> 19) == B)
      atomicAdd(&lh2[(dv >> 5) & 0x3FFFu], 1u);
  }
  __syncthreads();
  {
    int base = threadIdx.x * 16;
    uint32_t s = 0;
    for (int i = 0; i < 16; ++i) s += lh2[base + i];
    ls[threadIdx.x] = s;
    __syncthreads();
    for (int off = 1; off < 1024; off <<= 1) {
      uint32_t v = (threadIdx.x >= off) ? ls[threadIdx.x - off] : 0u;
      __syncthreads();
      ls[threadIdx.x] += v;
      __syncthreads();
    }
    uint32_t incl = ls[threadIdx.x];
    uint32_t excl = incl - s;
    if (excl < target && target <= incl) {
      uint32_t cum = excl;
      for (int i = 0; i < 16; ++i) {
        uint32_t c = lh2[base + i];
        if (cum + c >= target) {
          stateT[b] = (B << 19) | ((uint32_t)(base + i) << 5) | 0x1Fu;
          break;
        }
        cum += c;
      }
    }
  }
}

// LDS-staged winner gather + interleaved output zeroing (R8-proven placement:
// 2048 blocks = full-chip store BW, no barrier coupling with the reads).
__global__ __launch_bounds__(256) void k_gather(const uint32_t* __restrict__ d,
                                                const uint32_t* __restrict__ stateT,
                                                uint32_t* __restrict__ cnt,
                                                unsigned long long* __restrict__ winners,
                                                f32x4* __restrict__ outz) {
  __shared__ unsigned long long buf[GBLK];
  __shared__ uint32_t lcnt;
  __shared__ uint32_t gbase;
  int base = blockIdx.x * GBLK;
  int b = base >> 18;
  uint32_t T = stateT[b];
  uint32_t gt = (uint32_t)blockIdx.x * 256u + threadIdx.x;
  const f32x4 z4 = {0.f, 0.f, 0.f, 0.f};
  if (threadIdx.x == 0) lcnt = 0u;
  __syncthreads();
  for (int it = 0; it < GBLK / 256; ++it) {       // 16 iterations
    int p = base + it * 256 + threadIdx.x;
    uint32_t dv = d[p];
    outz[(uint32_t)it * GTHREADS + gt] = z4;      // zero-fill ride-along
    if (dv <= T) {
      uint32_t pos = atomicAdd(&lcnt, 1u);
      buf[pos] = ((unsigned long long)dv << 32) |
                 (unsigned long long)(p & (HW - 1));
    }
  }
  { uint32_t z = 16u * GTHREADS + gt;             // tail: 32768 float4s
    if (z < OUT_F4) outz[z] = z4; }
  __syncthreads();
  uint32_t n = lcnt;
  if (threadIdx.x == 0 && n) gbase = atomicAdd(&cnt[b], n);
  __syncthreads();
  for (uint32_t i = threadIdx.x; i < n; i += 256) {
    uint32_t pos = gbase + i;
    if (pos < 8192u) winners[(size_t)b * 8192 + pos] = buf[i];
  }
}

// sort each 1024-chunk ascending; 1024 threads = one compare-exchange per
// thread per pass (R8-verified).
__global__ __launch_bounds__(1024) void k_sort1(const uint32_t* __restrict__ cnt,
                                                unsigned long long* __restrict__ winners) {
  __shared__ unsigned long long s[1024];
  int blk = blockIdx.x;
  int b = blk >> 3;
  int c = blk & 7;
  uint32_t n = cnt[b];
  if (n > 8192u) n = 8192u;
  int goff = b * 8192 + c * 1024;
  int t = threadIdx.x;
  s[t] = ((uint32_t)(c * 1024 + t) < n) ? winners[goff + t]
                                        : 0xFFFFFFFFFFFFFFFFull;
  __syncthreads();
  for (int k = 2; k <= 1024; k <<= 1) {
    for (int j = k >> 1; j > 0; j >>= 1) {
      int ixj = t ^ j;
      if (ixj > t) {
        bool up = ((t & k) == 0);
        unsigned long long a = s[t];
        unsigned long long cc = s[ixj];
        if ((a > cc) == up) { s[t] = cc; s[ixj] = a; }
      }
      __syncthreads();
    }
  }
  winners[goff + t] = s[t];
}

// exact rank via 7 binary searches/winner + scatter; 8 blocks per batch
// (R8-verified).
__global__ __launch_bounds__(1024) void k_rank(const unsigned long long* __restrict__ winners,
                                               const float* __restrict__ flows,
                                               float* __restrict__ out0,
                                               float* __restrict__ out_idx,
                                               float* __restrict__ out_masks) {
  __shared__ unsigned long long s[8192];
  int b = blockIdx.x >> 3;
  int part = blockIdx.x & 7;
  for (int i = threadIdx.x; i < 8192; i += 1024)
    s[i] = winners[(size_t)b * 8192 + i];
  __syncthreads();
  const float* fb = flows + ((size_t)b << 19);
  int i = (part << 10) + threadIdx.x;              // this block's winner
  unsigned long long w = s[i];
  if (w != 0xFFFFFFFFFFFFFFFFull) {
    int rank = threadIdx.x;                        // position in own chunk
    for (int c = 0; c < 8; ++c) {
      if (c == part) continue;
      int lo = 0, hi = 1024;
      while (lo < hi) {
        int mid = (lo + hi) >> 1;
        if (s[(c << 10) + mid] < w) lo = mid + 1; else hi = mid;
      }
      rank += lo;
    }
    if (rank < TOPK) {
      uint32_t idx = (uint32_t)(w & 0xFFFFFFFFull);
      out_idx[(size_t)b * TOPK + rank] = (float)idx;
      float x = fb[idx];
      float y = fb[idx + HW];
      size_t o = ((size_t)b * 3) * HW + idx;
      out0[o] = x;
      out0[o + HW] = y;
      out0[o + 2 * HW] = 1.0f;
      out_masks[(size_t)b * HW + idx] = 1.0f;
    }
  }
}

extern "C" void kernel_launch(void* const* d_in, const int* in_sizes, int n_in,
                              void* d_out, int out_size, void* d_ws, size_t ws_size,
                              hipStream_t stream) {
  const float* flows = (const float*)d_in[0];
  float* out = (float*)d_out;
  char* ws = (char*)d_ws;

  uint32_t* d = (uint32_t*)ws;
  unsigned long long* winners = (unsigned long long*)(ws + OFF_WIN);
  uint16_t* histP = (uint16_t*)(ws + OFF_HP);
  uint32_t* stateA = (uint32_t*)(ws + OFF_STA);
  uint32_t* stateT = (uint32_t*)(ws + OFF_STT);
  uint32_t* flag = (uint32_t*)(ws + OFF_FLG);
  uint32_t* cnt = (uint32_t*)(ws + OFF_CNT);

  float* out_idx = out + (size_t)NB * 3 * HW;        // 25,165,824
  float* out_masks = out_idx + (size_t)NB * TOPK;    // 25,296,896

  // No memsets (R12): private hists need no pre-zero, cnt zeroed by scanAB,
  // fallback hist lives in LDS, output zeroing rides in gather.
  k_compute<<<NTOTAL / CBLK, 1024, 0, stream>>>(flows, d, histP);
  k_scanAB<<<NB, 1024, 0, stream>>>(histP, d, stateA, stateT, flag, cnt);
  k_gather<<<NTOTAL / GBLK, 256, 0, stream>>>(d, stateT, cnt, winners,
                                              (f32x4*)out);
  k_sort1<<<NB * 8, 1024, 0, stream>>>(cnt, winners);
  k_rank<<<NB * 8, 1024, 0, stream>>>(winners, flows, out, out_idx, out_masks);
}